// Round 3
// baseline (234.817 us; speedup 1.0000x reference)
//
#include <hip/hip_runtime.h>
#include <math.h>

typedef float v2f __attribute__((ext_vector_type(2)));

namespace {
constexpr int   M1 = 12;     // basis per dim
constexpr float LB = 4.5f;   // HSGP half-domain L = c * S = 1.5 * 3.0
}

// ---------------------------------------------------------------------------
// Setup: fold spectral-density sqrt weights + norm into beta, laid out per
// lane-class q = (a_half*2 + j_half):
//   Bs[q*108 + ((r*3 + d)*3 + jp)*2 + p] = B(a = 6*(q>>1)+r, d, j = 6*(q&1)+2*jp+p)
// ---------------------------------------------------------------------------
__global__ void setup_B_kernel(const float* __restrict__ beta,
                               const float* __restrict__ ls,
                               const float* __restrict__ alpha,
                               float* __restrict__ Bs) {
    int idx = blockIdx.x * blockDim.x + threadIdx.x;
    if (idx >= 432) return;
    int q   = idx / 108;
    int rem = idx - q * 108;
    int pi  = rem >> 1;
    int p   = rem & 1;
    int r   = pi / 9;
    int d   = (pi % 9) / 3;
    int jp  = pi % 3;
    int a = (q >> 1) * 6 + r;
    int j = (q & 1) * 6 + jp * 2 + p;
    float w0 = (float)M_PI * (float)(a + 1) / (2.0f * LB);
    float w1 = (float)M_PI * (float)(j + 1) / (2.0f * LB);
    float l0 = ls[0], l1 = ls[1], al = alpha[0];
    float S = al * al * (2.0f * (float)M_PI) * l0 * l1 *
              expf(-0.5f * (l0 * l0 * w0 * w0 + l1 * l1 * w1 * w1));
    Bs[idx] = beta[d * (M1 * M1) + a * M1 + j] * sqrtf(S) * (1.0f / LB);
}

// ---------------------------------------------------------------------------
// quad (4-lane) butterfly sum via DPP quad_perm — pure VALU, no LDS
// ---------------------------------------------------------------------------
__device__ __forceinline__ float quad_sum(float v) {
    int t = __builtin_amdgcn_mov_dpp(__float_as_int(v), 0xB1, 0xF, 0xF, true); // [1,0,3,2]
    v += __int_as_float(t);
    t = __builtin_amdgcn_mov_dpp(__float_as_int(v), 0x4E, 0xF, 0xF, true);     // [2,3,0,1]
    v += __int_as_float(t);
    return v;
}

// ---------------------------------------------------------------------------
// 3 packed (sin, W*m*cos) pairs for multiples m = bm+1 .. bm+6 of angle th.
// ps[k] = (sin((bm+2k+1)th), sin((bm+2k+2)th)); pwc[k] = pkW[k] * cos-pair.
// ---------------------------------------------------------------------------
__device__ __forceinline__ void trig3(float th, float bm, const v2f* pkW,
                                      v2f* ps, v2f* pwc) {
    float s1 = __sinf(th), c1 = __cosf(th);
    float sb = __sinf(bm * th), cb = __cosf(bm * th);
    float sA = fmaf(sb, c1,  cb * s1);           // bm+1
    float cA = fmaf(cb, c1, -(sb * s1));
    float sB = fmaf(sA, c1,  cA * s1);           // bm+2
    float cB = fmaf(cA, c1, -(sA * s1));
    float s2 = 2.0f * s1 * c1;                   // double angle for packed step
    float c2 = fmaf(-2.0f * s1, s1, 1.0f);
    v2f P = (v2f){sA, sB}, C = (v2f){cA, cB};
    v2f c2p = (v2f){c2, c2}, s2p = (v2f){s2, s2};
    ps[0] = P; pwc[0] = pkW[0] * C;
    v2f P1 = __builtin_elementwise_fma(P, c2p, C * s2p);
    v2f C1 = __builtin_elementwise_fma(C, c2p, -(P * s2p));
    ps[1] = P1; pwc[1] = pkW[1] * C1;
    v2f P2 = __builtin_elementwise_fma(P1, c2p, C1 * s2p);
    v2f C2 = __builtin_elementwise_fma(C1, c2p, -(P1 * s2p));
    ps[2] = P2; pwc[2] = pkW[2] * C2;
}

// ---------------------------------------------------------------------------
// Main: 4 lanes per element; lane q = (a_half<<1)|j_half owns a 6x6 block of
// the 12x12 basis grid. B-block pinned in VGPRs (no in-loop reloads).
// ---------------------------------------------------------------------------
__global__ __launch_bounds__(64, 2)
void geo_kernel(const float* __restrict__ xg, const float* __restrict__ vg,
                const float* Bs /* intentionally non-restrict: pins pB */,
                float* __restrict__ out, int B)
{
    int tid = blockIdx.x * 64 + threadIdx.x;
    int e = tid >> 2;
    if (e >= B) return;
    int q  = tid & 3;
    int qa = q >> 1, qj = q & 1;

    const float W = (float)M_PI / (2.0f * LB);
    float bm0 = (float)(6 * qa);
    float bm1 = (float)(6 * qj);
    v2f pkW0[3], pkW1[3];
    #pragma unroll
    for (int k = 0; k < 3; ++k) {
        pkW0[k] = (v2f){W * (bm0 + (float)(2 * k + 1)), W * (bm0 + (float)(2 * k + 2))};
        pkW1[k] = (v2f){W * (bm1 + (float)(2 * k + 1)), W * (bm1 + (float)(2 * k + 2))};
    }

    // ---- preload this lane's 6x6 B-block (pairs over j): 54 v2f ----
    v2f pB[6][3][3];
    {
        const v2f* src = reinterpret_cast<const v2f*>(Bs) + q * 54;
        #pragma unroll
        for (int r = 0; r < 6; ++r)
            #pragma unroll
            for (int d = 0; d < 3; ++d)
                #pragma unroll
                for (int jp = 0; jp < 3; ++jp)
                    pB[r][d][jp] = src[(r * 3 + d) * 3 + jp];
    }
    // memory clobber: reloading Bs past this point is unsound -> pB stays in regs
    asm volatile("" ::: "memory");

    float2 xv = reinterpret_cast<const float2*>(xg)[e];
    float2 vv2 = reinterpret_cast<const float2*>(vg)[e];
    float x0 = xv.x, x1 = xv.y, v0 = vv2.x, v1 = vv2.y;

    // per-lane scalar output slot: out[t][q>>1][e][q&1]
    unsigned off = 4u * ((((unsigned)qa * (unsigned)B) + (unsigned)e) * 2u + (unsigned)qj);
    const unsigned stride = 16u * (unsigned)B;      // bytes per time slot
    char* outc = reinterpret_cast<char*>(out);
    {
        float sval = (q & 2) ? ((q & 1) ? v1 : v0) : ((q & 1) ? x1 : x0);
        *reinterpret_cast<float*>(outc + off) = sval;
    }

    // Adams histories (older entries), named regs
    float h1x = 0.f, h2x = 0.f, h3x = 0.f, h1y = 0.f, h2y = 0.f, h3y = 0.f;
    float g1x = 0.f, g2x = 0.f, g3x = 0.f, g1y = 0.f, g2y = 0.f, g3y = 0.f;
    const float h = 1.0f / 99.0f;

    auto STEP = [&](float c0, float c1c, float c2c, float c3c) {
        v2f ps0[3], pwc0[3], ps1[3], pwc1[3];
        trig3(W * (x0 + LB), bm0, pkW0, ps0, pwc0);
        trig3(W * (x1 + LB), bm1, pkW1, ps1, pwc1);

        v2f pf0{0,0}, pf1{0,0}, pf2{0,0};
        v2f pdA0{0,0}, pdA1{0,0}, pdA2{0,0};
        v2f pdB0{0,0}, pdB1{0,0}, pdB2{0,0};
        #pragma unroll
        for (int r = 0; r < 6; ++r) {
            float sA = (r & 1) ? ps0[r >> 1].y : ps0[r >> 1].x;
            float cA = (r & 1) ? pwc0[r >> 1].y : pwc0[r >> 1].x;
            v2f aS0{0,0}, aS1{0,0}, aS2{0,0}, aC0{0,0}, aC1{0,0}, aC2{0,0};
            #pragma unroll
            for (int jp = 0; jp < 3; ++jp) {
                v2f s = ps1[jp], c = pwc1[jp];
                aS0 = __builtin_elementwise_fma(pB[r][0][jp], s, aS0);
                aC0 = __builtin_elementwise_fma(pB[r][0][jp], c, aC0);
                aS1 = __builtin_elementwise_fma(pB[r][1][jp], s, aS1);
                aC1 = __builtin_elementwise_fma(pB[r][1][jp], c, aC1);
                aS2 = __builtin_elementwise_fma(pB[r][2][jp], s, aS2);
                aC2 = __builtin_elementwise_fma(pB[r][2][jp], c, aC2);
            }
            v2f sAp = (v2f){sA, sA}, cAp = (v2f){cA, cA};
            pf0  = __builtin_elementwise_fma(sAp, aS0, pf0);
            pf1  = __builtin_elementwise_fma(sAp, aS1, pf1);
            pf2  = __builtin_elementwise_fma(sAp, aS2, pf2);
            pdA0 = __builtin_elementwise_fma(cAp, aS0, pdA0);
            pdA1 = __builtin_elementwise_fma(cAp, aS1, pdA1);
            pdA2 = __builtin_elementwise_fma(cAp, aS2, pdA2);
            pdB0 = __builtin_elementwise_fma(sAp, aC0, pdB0);
            pdB1 = __builtin_elementwise_fma(sAp, aC1, pdB1);
            pdB2 = __builtin_elementwise_fma(sAp, aC2, pdB2);
        }
        float f0 = pf0.x + pf0.y, f1 = pf1.x + pf1.y, f2 = pf2.x + pf2.y;
        float dA0 = pdA0.x + pdA0.y, dA1 = pdA1.x + pdA1.y, dA2 = pdA2.x + pdA2.y;
        float dB0 = pdB0.x + pdB0.y, dB1 = pdB1.x + pdB1.y, dB2 = pdB2.x + pdB2.y;

        // fold vv (quad-uniform) BEFORE the quad reduction: only 5 quad_sums
        float vv00 = v0 * v0, vv01 = v0 * v1, vv11 = v1 * v1;
        float q0p = dA0 * vv00 + 2.0f * dB0 * vv01 + fmaf(2.0f, dB1, -dA2) * vv11;
        float q1p = fmaf(2.0f, dA1, -dB0) * vv00 + 2.0f * dA2 * vv01 + dB2 * vv11;

        f0 = quad_sum(f0); f1 = quad_sum(f1); f2 = quad_sum(f2);
        float q0s = quad_sum(q0p), q1s = quad_sum(q1p);

        float G00 = f0 + 1.0f, G01 = f1, G11 = f2 + 1.0f;
        float det = fmaf(G00, G11, -(G01 * G01));
        float rdet = __builtin_amdgcn_rcpf(det);
        float a0 = -0.5f * rdet * fmaf(G11, q0s, -(G01 * q1s));
        float a1 = -0.5f * rdet * fmaf(G00, q1s, -(G01 * q0s));

        // AB combine: newest derivative is (v, a); histories are older
        float dx0 = fmaf(c0, v0, fmaf(c1c, h1x, fmaf(c2c, h2x, c3c * h3x)));
        float dx1 = fmaf(c0, v1, fmaf(c1c, h1y, fmaf(c2c, h2y, c3c * h3y)));
        float dv0 = fmaf(c0, a0, fmaf(c1c, g1x, fmaf(c2c, g2x, c3c * g3x)));
        float dv1 = fmaf(c0, a1, fmaf(c1c, g1y, fmaf(c2c, g2y, c3c * g3y)));
        h3x = h2x; h2x = h1x; h1x = v0;  h3y = h2y; h2y = h1y; h1y = v1;
        g3x = g2x; g2x = g1x; g1x = a0;  g3y = g2y; g2y = g1y; g1y = a1;
        x0 = fmaf(h, dx0, x0); x1 = fmaf(h, dx1, x1);
        v0 = fmaf(h, dv0, v0); v1 = fmaf(h, dv1, v1);

        off += stride;
        float sval = (q & 2) ? ((q & 1) ? v1 : v0) : ((q & 1) ? x1 : x0);
        *reinterpret_cast<float*>(outc + off) = sval;
    };

    // startup (orders 1..3), then steady AB4
    STEP(1.0f, 0.0f, 0.0f, 0.0f);
    STEP(1.5f, -0.5f, 0.0f, 0.0f);
    STEP(23.0f / 12.0f, -16.0f / 12.0f, 5.0f / 12.0f, 0.0f);
    #pragma unroll 4
    for (int t = 3; t < 99; ++t)
        STEP(55.0f / 24.0f, -59.0f / 24.0f, 37.0f / 24.0f, -9.0f / 24.0f);
}

// ---------------------------------------------------------------------------
extern "C" void kernel_launch(void* const* d_in, const int* in_sizes, int n_in,
                              void* d_out, int out_size, void* d_ws, size_t ws_size,
                              hipStream_t stream) {
    const float* x0    = (const float*)d_in[0];
    const float* v0    = (const float*)d_in[1];
    const float* beta  = (const float*)d_in[2];
    const float* ls    = (const float*)d_in[3];
    const float* alpha = (const float*)d_in[4];
    float* out = (float*)d_out;
    float* Bs  = (float*)d_ws;   // 432 floats, per-lane-class layout

    int B = in_sizes[0] / 2;     // 50000

    hipLaunchKernelGGL(setup_B_kernel, dim3(7), dim3(64), 0, stream,
                       beta, ls, alpha, Bs);

    long threads = 4L * B;
    int grid = (int)((threads + 63) / 64);
    hipLaunchKernelGGL(geo_kernel, dim3(grid), dim3(64), 0, stream,
                       x0, v0, Bs, out, B);
}